// Round 1
// baseline (141.515 us; speedup 1.0000x reference)
//
#include <hip/hip_runtime.h>
#include <math.h>

// Problem constants (fixed by the reference):
#define NROWS 65536   // B*H*Wd = 8*64*128
#define DD    272     // capsule feature dim
#define NC    19      // num classes
#define NP    524288  // total points
#define NSEG  4096    // total instances
#define PS    20      // padded proj row stride (16B-aligned float4 rows)

// ---------------------------------------------------------------------------
// Kernel A: proj[row][c] = sum_d X[row][d] * W[d][c], proj padded to stride 20
// 1024 blocks x 256 threads; 64 rows per block; wave q handles d % 4 == q.
// ---------------------------------------------------------------------------
__global__ __launch_bounds__(256) void proj_kernel(
    const float* __restrict__ X, const float* __restrict__ W,
    float* __restrict__ proj) {
  const int t    = threadIdx.x;
  const int lane = t & 63;
  // readfirstlane => compiler-provable wave-uniform residue => scalar W loads
  const int q    = __builtin_amdgcn_readfirstlane(t >> 6);
  const int row0 = blockIdx.x * 64;

  __shared__ float Xs[64 * 17];        // 64 rows x 16 floats, pad stride 17
  __shared__ float R[4 * 64 * NC];     // per-wave partials for reduction

  float acc[NC];
#pragma unroll
  for (int c = 0; c < NC; ++c) acc[c] = 0.f;

  const int r_ld = t >> 2;             // staging: row
  const int c4   = t & 3;              // staging: float4 slot within 16 floats
  const float* gsrc = X + (size_t)(row0 + r_ld) * DD + c4 * 4;

  for (int chunk = 0; chunk < 17; ++chunk) {
    float4 v = *(const float4*)(gsrc + chunk * 16);  // coalesced dwordx4
    __syncthreads();                   // protect previous chunk's reads
    float* dst = &Xs[r_ld * 17 + c4 * 4];
    dst[0] = v.x; dst[1] = v.y; dst[2] = v.z; dst[3] = v.w;
    __syncthreads();
    const int d0 = chunk * 16;
#pragma unroll
    for (int k = 0; k < 4; ++k) {
      const int c16 = q + 4 * k;                     // wave-uniform
      const float x = Xs[lane * 17 + c16];           // stride 17: 2-way, free
      const float* wr = W + (d0 + c16) * NC;         // uniform -> s_load
#pragma unroll
      for (int c = 0; c < NC; ++c) acc[c] = fmaf(x, wr[c], acc[c]);
    }
  }

  // cross-wave reduction of the 4 d-residue partials
#pragma unroll
  for (int c = 0; c < NC; ++c) R[(q * 64 + lane) * NC + c] = acc[c];
  __syncthreads();
#pragma unroll
  for (int j = 0; j < 5; ++j) {
    int f = t + 256 * j;               // 0..1279 covers 64 rows x 20 cols
    int r = f / PS;
    int c = f % PS;
    float s = 0.f;
    if (c < NC) {
      s = R[r * NC + c] + R[(64 + r) * NC + c] +
          R[(128 + r) * NC + c] + R[(192 + r) * NC + c];
    }
    proj[(size_t)row0 * PS + f] = s;   // contiguous coalesced store (pad = 0)
  }
}

// ---------------------------------------------------------------------------
// Kernel B: per-segment mean of gathered proj rows + bias + sigmoid.
// One wave per segment; segment_ids sorted => binary-search bounds.
// ---------------------------------------------------------------------------
__global__ __launch_bounds__(64) void pool_kernel(
    const float* __restrict__ proj, const int* __restrict__ point_idx,
    const int* __restrict__ seg, const float* __restrict__ bias,
    float* __restrict__ out) {
  const int s    = blockIdx.x;
  const int lane = threadIdx.x;

  // lower_bound(seg, s) and lower_bound(seg, s+1)
  int lo = 0, hi = NP;
  while (lo < hi) { int mid = (lo + hi) >> 1; if (seg[mid] <  s) lo = mid + 1; else hi = mid; }
  const int start = lo;
  hi = NP;
  while (lo < hi) { int mid = (lo + hi) >> 1; if (seg[mid] <= s) lo = mid + 1; else hi = mid; }
  const int end = lo;

  float a[PS];
#pragma unroll
  for (int j = 0; j < PS; ++j) a[j] = 0.f;

  for (int p = start + lane; p < end; p += 64) {
    const int pi = point_idx[p];
    const float4* row = (const float4*)(proj + (size_t)pi * PS);  // 80B aligned
#pragma unroll
    for (int j = 0; j < 5; ++j) {
      float4 v = row[j];
      a[4 * j + 0] += v.x; a[4 * j + 1] += v.y;
      a[4 * j + 2] += v.z; a[4 * j + 3] += v.w;
    }
  }

  // butterfly reduce the 19 live accumulators across 64 lanes
#pragma unroll
  for (int off = 32; off > 0; off >>= 1) {
#pragma unroll
    for (int j = 0; j < NC; ++j) a[j] += __shfl_xor(a[j], off);
  }

  if (lane == 0) {
    const float inv = 1.f / fmaxf((float)(end - start), 1.f);
#pragma unroll
    for (int c = 0; c < NC; ++c) {
      float m = a[c] * inv + bias[c];
      out[s * NC + c] = 1.f / (1.f + expf(-m));
    }
  }
}

// ---------------------------------------------------------------------------
// Fallback (only if workspace is too small): direct full-D gather per segment.
// ---------------------------------------------------------------------------
__global__ __launch_bounds__(256) void fallback_kernel(
    const float* __restrict__ X, const float* __restrict__ W,
    const float* __restrict__ bias, const int* __restrict__ point_idx,
    const int* __restrict__ seg, float* __restrict__ out) {
  const int s = blockIdx.x;
  const int t = threadIdx.x;
  __shared__ float Ps[DD];

  int lo = 0, hi = NP;
  while (lo < hi) { int mid = (lo + hi) >> 1; if (seg[mid] <  s) lo = mid + 1; else hi = mid; }
  const int start = lo;
  hi = NP;
  while (lo < hi) { int mid = (lo + hi) >> 1; if (seg[mid] <= s) lo = mid + 1; else hi = mid; }
  const int end = lo;

  float a0 = 0.f, a1 = 0.f;
  for (int p = start; p < end; ++p) {
    const int pi = point_idx[p];
    const float* row = X + (size_t)pi * DD;
    a0 += row[t];
    if (t < DD - 256) a1 += row[256 + t];
  }
  const float inv = 1.f / fmaxf((float)(end - start), 1.f);
  Ps[t] = a0 * inv;
  if (t < DD - 256) Ps[256 + t] = a1 * inv;
  __syncthreads();

  if (t < NC) {
    float acc = bias[t];
    for (int d = 0; d < DD; ++d) acc = fmaf(Ps[d], W[d * NC + t], acc);
    out[s * NC + t] = 1.f / (1.f + expf(-acc));
  }
}

extern "C" void kernel_launch(void* const* d_in, const int* in_sizes, int n_in,
                              void* d_out, int out_size, void* d_ws, size_t ws_size,
                              hipStream_t stream) {
  const float* X         = (const float*)d_in[0];  // [65536, 272]
  const float* W         = (const float*)d_in[1];  // [272, 19]
  const float* bias      = (const float*)d_in[2];  // [19]
  const int*   point_idx = (const int*)d_in[3];    // [P]
  const int*   seg       = (const int*)d_in[4];    // [P] sorted
  float*       out       = (float*)d_out;          // [4096, 19]

  const size_t need = (size_t)NROWS * PS * sizeof(float);  // 5 MB proj
  if (ws_size >= need) {
    float* proj = (float*)d_ws;
    proj_kernel<<<NROWS / 64, 256, 0, stream>>>(X, W, proj);
    pool_kernel<<<NSEG, 64, 0, stream>>>(proj, point_idx, seg, bias, out);
  } else {
    fallback_kernel<<<NSEG, 256, 0, stream>>>(X, W, bias, point_idx, seg, out);
  }
}

// Round 2
// 128.694 us; speedup vs baseline: 1.0996x; 1.0996x over previous
//
#include <hip/hip_runtime.h>
#include <math.h>

// Problem constants (fixed by the reference):
#define NROWS 65536   // B*H*Wd = 8*64*128
#define DD    272     // capsule feature dim
#define NC    19      // num classes
#define NP    524288  // total points
#define NSEG  4096    // total instances
#define PS    20      // padded proj row stride (16B-aligned float4 rows)

#define PROJ_BLOCKS   (NROWS / 64)     // 1024
#define BOUND_BLOCKS  (NP / 256)       // 2048

// ---------------------------------------------------------------------------
// Fused kernel A:
//   blocks [0, 1024): proj[row][c] = sum_d X[row][d] * W[d][c]  (stride-20 pad)
//     64 rows/block, 256 threads; wave q handles d % 4 == q; one-chunk-ahead
//     global prefetch so HBM latency overlaps the FMA loop.
//   blocks [1024, 3072): segment boundary extraction from sorted seg[]:
//     bnd[s] = lower_bound(seg, s); bnd[NSEG] = NP.
// ---------------------------------------------------------------------------
__global__ __launch_bounds__(256) void proj_bounds_kernel(
    const float* __restrict__ X, const float* __restrict__ W,
    const int* __restrict__ seg, float* __restrict__ proj,
    int* __restrict__ bnd) {
  const int t = threadIdx.x;

  if (blockIdx.x >= PROJ_BLOCKS) {
    // ---- boundary extraction ----
    const int p = (blockIdx.x - PROJ_BLOCKS) * 256 + t;
    const int cur  = seg[p];
    const int prev = (p == 0) ? -1 : seg[p - 1];
    for (int s = prev + 1; s <= cur; ++s) bnd[s] = p;   // total writes <= NSEG+1
    if (p == NP - 1) {
      for (int s = cur + 1; s <= NSEG; ++s) bnd[s] = NP;
    }
    return;
  }

  // ---- projection GEMM ----
  const int lane = t & 63;
  const int q    = __builtin_amdgcn_readfirstlane(t >> 6);  // wave-uniform residue
  const int row0 = blockIdx.x * 64;

  __shared__ float Xs[64 * 17];        // 64 rows x 16 floats, pad stride 17
  __shared__ float R[4 * 64 * NC];     // per-wave partials for reduction

  float acc[NC];
#pragma unroll
  for (int c = 0; c < NC; ++c) acc[c] = 0.f;

  const int r_ld = t >> 2;             // staging row
  const int c4   = t & 3;              // float4 slot within 16-float chunk
  const float* gsrc = X + (size_t)(row0 + r_ld) * DD + c4 * 4;

  float4 v = *(const float4*)gsrc;     // prefetch chunk 0

  for (int chunk = 0; chunk < 17; ++chunk) {
    __syncthreads();                   // previous chunk's Xs reads done
    float* dst = &Xs[r_ld * 17 + c4 * 4];
    dst[0] = v.x; dst[1] = v.y; dst[2] = v.z; dst[3] = v.w;
    __syncthreads();
    if (chunk < 16)                    // issue next chunk's load BEFORE compute
      v = *(const float4*)(gsrc + (chunk + 1) * 16);
    const int d0 = chunk * 16;
#pragma unroll
    for (int k = 0; k < 4; ++k) {
      const int c16 = q + 4 * k;                     // wave-uniform
      const float x = Xs[lane * 17 + c16];           // stride 17: 2-way, free
      const float* wr = W + (d0 + c16) * NC;         // uniform -> s_load
#pragma unroll
      for (int c = 0; c < NC; ++c) acc[c] = fmaf(x, wr[c], acc[c]);
    }
  }

  // cross-wave reduction of the 4 d-residue partials
#pragma unroll
  for (int c = 0; c < NC; ++c) R[(q * 64 + lane) * NC + c] = acc[c];
  __syncthreads();
#pragma unroll
  for (int j = 0; j < 5; ++j) {
    int f = t + 256 * j;               // 0..1279 covers 64 rows x 20 cols
    int r = f / PS;
    int c = f % PS;
    float s = 0.f;
    if (c < NC) {
      s = R[r * NC + c] + R[(64 + r) * NC + c] +
          R[(128 + r) * NC + c] + R[(192 + r) * NC + c];
    }
    proj[(size_t)row0 * PS + f] = s;   // contiguous coalesced store (pad = 0)
  }
}

// ---------------------------------------------------------------------------
// Kernel B: per-segment mean of gathered proj rows + bias + sigmoid.
// One wave per segment; boundaries come from bnd[] (two scalar loads).
// ---------------------------------------------------------------------------
__global__ __launch_bounds__(64) void pool_kernel(
    const float* __restrict__ proj, const int* __restrict__ point_idx,
    const int* __restrict__ bnd, const float* __restrict__ bias,
    float* __restrict__ out) {
  const int s    = blockIdx.x;
  const int lane = threadIdx.x;
  const int start = bnd[s];
  const int end   = bnd[s + 1];

  float a[PS];
#pragma unroll
  for (int j = 0; j < PS; ++j) a[j] = 0.f;

  for (int p = start + lane; p < end; p += 64) {
    const int pi = point_idx[p];
    const float4* row = (const float4*)(proj + (size_t)pi * PS);  // 80B aligned
#pragma unroll
    for (int j = 0; j < 5; ++j) {
      float4 v = row[j];
      a[4 * j + 0] += v.x; a[4 * j + 1] += v.y;
      a[4 * j + 2] += v.z; a[4 * j + 3] += v.w;
    }
  }

  // butterfly reduce the 19 live accumulators across 64 lanes
#pragma unroll
  for (int off = 32; off > 0; off >>= 1) {
#pragma unroll
    for (int j = 0; j < NC; ++j) a[j] += __shfl_xor(a[j], off);
  }

  if (lane == 0) {
    const float inv = 1.f / fmaxf((float)(end - start), 1.f);
#pragma unroll
    for (int c = 0; c < NC; ++c) {
      float m = a[c] * inv + bias[c];
      out[s * NC + c] = 1.f / (1.f + expf(-m));
    }
  }
}

// ---------------------------------------------------------------------------
// Fallback (only if workspace is too small): direct full-D gather per segment.
// ---------------------------------------------------------------------------
__global__ __launch_bounds__(256) void fallback_kernel(
    const float* __restrict__ X, const float* __restrict__ W,
    const float* __restrict__ bias, const int* __restrict__ point_idx,
    const int* __restrict__ seg, float* __restrict__ out) {
  const int s = blockIdx.x;
  const int t = threadIdx.x;
  __shared__ float Ps[DD];

  int lo = 0, hi = NP;
  while (lo < hi) { int mid = (lo + hi) >> 1; if (seg[mid] <  s) lo = mid + 1; else hi = mid; }
  const int start = lo;
  hi = NP;
  while (lo < hi) { int mid = (lo + hi) >> 1; if (seg[mid] <= s) lo = mid + 1; else hi = mid; }
  const int end = lo;

  float a0 = 0.f, a1 = 0.f;
  for (int p = start; p < end; ++p) {
    const int pi = point_idx[p];
    const float* row = X + (size_t)pi * DD;
    a0 += row[t];
    if (t < DD - 256) a1 += row[256 + t];
  }
  const float inv = 1.f / fmaxf((float)(end - start), 1.f);
  Ps[t] = a0 * inv;
  if (t < DD - 256) Ps[256 + t] = a1 * inv;
  __syncthreads();

  if (t < NC) {
    float acc = bias[t];
    for (int d = 0; d < DD; ++d) acc = fmaf(Ps[d], W[d * NC + t], acc);
    out[s * NC + t] = 1.f / (1.f + expf(-acc));
  }
}

extern "C" void kernel_launch(void* const* d_in, const int* in_sizes, int n_in,
                              void* d_out, int out_size, void* d_ws, size_t ws_size,
                              hipStream_t stream) {
  const float* X         = (const float*)d_in[0];  // [65536, 272]
  const float* W         = (const float*)d_in[1];  // [272, 19]
  const float* bias      = (const float*)d_in[2];  // [19]
  const int*   point_idx = (const int*)d_in[3];    // [P]
  const int*   seg       = (const int*)d_in[4];    // [P] sorted
  float*       out       = (float*)d_out;          // [4096, 19]

  const size_t proj_bytes = (size_t)NROWS * PS * sizeof(float);     // 5.24 MB
  const size_t need = proj_bytes + (size_t)(NSEG + 1) * sizeof(int);
  if (ws_size >= need) {
    float* proj = (float*)d_ws;
    int*   bnd  = (int*)((char*)d_ws + proj_bytes);
    proj_bounds_kernel<<<PROJ_BLOCKS + BOUND_BLOCKS, 256, 0, stream>>>(
        X, W, seg, proj, bnd);
    pool_kernel<<<NSEG, 64, 0, stream>>>(proj, point_idx, bnd, bias, out);
  } else {
    fallback_kernel<<<NSEG, 256, 0, stream>>>(X, W, bias, point_idx, seg, out);
  }
}